// Round 5
// baseline (153.391 us; speedup 1.0000x reference)
//
#include <hip/hip_runtime.h>
#include <hip/hip_bf16.h>
#include <hip/hip_fp16.h>

// Problem constants (AttentionModule: B=16, idf=128, cdf=256, H=W=128, L=64)
#define NB  16
#define IDF 128
#define CDF 256
#define LL  64
#define PP  16384      // H*W pixels per batch

typedef _Float16 f16;
typedef _Float16 f16x8 __attribute__((ext_vector_type(8)));
typedef float    f32x4 __attribute__((ext_vector_type(4)));

// ---------------------------------------------------------------------------
// Kernel 0: decode mask (int32 or uint8 on device) -> additive f32 table
// madd[16*64] (0 = keep, -inf = masked). Mask row used by pixel p is p%16
// (torch tile(mask,(P,1)) quirk) — verified in rounds 2-4.
// ---------------------------------------------------------------------------
__global__ void mask_prep_kernel(const unsigned char* __restrict__ mask_raw,
                                 float* __restrict__ madd) {
    __shared__ int is_u8;
    const int k = threadIdx.x;            // 0..1023, one block
    if (k == 0) is_u8 = 0;
    __syncthreads();
    const unsigned char byte = mask_raw[k];
    if ((k & 3) != 0 && byte != 0) atomicOr(&is_u8, 1);
    __syncthreads();
    int masked;
    if (is_u8) masked = (byte != 0);
    else       masked = (((const int*)mask_raw)[k] != 0);
    madd[k] = masked ? -INFINITY : 0.0f;
}

// ---------------------------------------------------------------------------
// Kernel 1: source = W @ context (fp32 accum), emitted as fp16 in BOTH
// orientations: srcF[b][i][l] (PV B-operand) and srcT[b][l][i] (QK^T A-op).
// ---------------------------------------------------------------------------
__global__ void src_pack_kernel(const float* __restrict__ Wm,
                                const float* __restrict__ ctx,
                                f16* __restrict__ srcF,
                                f16* __restrict__ srcT) {
    int g = blockIdx.x * 256 + threadIdx.x;      // 0 .. NB*IDF*LL-1
    int l = g & (LL - 1);
    int i = (g >> 6) & (IDF - 1);
    int b = g >> 13;
    const float* wrow = Wm + (size_t)i * CDF;
    const float* ccol = ctx + (size_t)b * CDF * LL + l;
    float s = 0.f;
    #pragma unroll 8
    for (int c = 0; c < CDF; ++c)
        s = fmaf(wrow[c], ccol[(size_t)c * LL], s);
    f16 h = (f16)s;
    srcF[g] = h;                                 // [b][i][l]
    srcT[((size_t)b * LL + l) * IDF + i] = h;    // [b][l][i]
}

// ---------------------------------------------------------------------------
// Kernel 2 (main): one wave = 16 pixels, end to end. No mask LDS, no
// initial barrier; all 32 x loads bulk-issued upfront (deep MLP).
//  QK^T: A = srcT (M=l), B = x (N=p).  D: l = mt*16+4g+r, p = pw+c.
//  softmax in registers (2 shfl_xor), mask fragment loaded from global.
//  PV (operands SWAPPED): A = prob (M=p, from per-wave LDS tile),
//      B = srcF (N=i).  D: p = pw+4g+r (contiguous!), i = mt*16+c
//      -> weight stores are float4 (16B/lane).
// ---------------------------------------------------------------------------
__global__ __launch_bounds__(256, 4)
void attn_mfma_kernel(const float* __restrict__ x,
                      const f16* __restrict__ srcT,
                      const f16* __restrict__ srcF,
                      const float* __restrict__ madd_g,
                      float* __restrict__ weight,
                      float* __restrict__ attn_out) {
    __shared__ __align__(16) f16 s_prob[4 * 16 * 72];  // per-wave [16 p][72] fp16

    const int b   = blockIdx.y;
    const int tid = threadIdx.x;
    const int wv   = tid >> 6;         // wave 0..3
    const int lane = tid & 63;
    const int c    = lane & 15;        // fragment row/col index
    const int g    = lane >> 4;        // k-slice group 0..3

    const int pw = blockIdx.x * 64 + wv * 16;            // wave's pixel base
    const float* xb = x + (size_t)b * IDF * PP + pw + c; // lane's x column

    // ---- bulk-issue ALL x loads (i = ks*32 + 8g + j), 32 dwords in flight
    float xf[32];
    #pragma unroll
    for (int ks = 0; ks < 4; ++ks)
        #pragma unroll
        for (int j = 0; j < 8; ++j)
            xf[ks * 8 + j] = xb[(size_t)(ks * 32 + 8 * g + j) * PP];

    // ---- mask fragment straight from global (row = p%16 = c)
    float4 mv[4];
    #pragma unroll
    for (int mt = 0; mt < 4; ++mt)
        mv[mt] = *reinterpret_cast<const float4*>(
            madd_g + c * LL + mt * 16 + 4 * g);

    // ---------------- QK^T ----------------
    const f16* srcT_b = srcT + (size_t)b * LL * IDF;
    f32x4 acc[4];
    #pragma unroll
    for (int mt = 0; mt < 4; ++mt) acc[mt] = (f32x4){0.f, 0.f, 0.f, 0.f};

    #pragma unroll
    for (int ks = 0; ks < 4; ++ks) {
        const int i0 = ks * 32 + 8 * g;
        f16x8 bf;
        #pragma unroll
        for (int j = 0; j < 8; ++j) bf[j] = (f16)xf[ks * 8 + j];
        #pragma unroll
        for (int mt = 0; mt < 4; ++mt) {
            const f16x8 af = *reinterpret_cast<const f16x8*>(
                srcT_b + (size_t)(mt * 16 + c) * IDF + i0);
            acc[mt] = __builtin_amdgcn_mfma_f32_16x16x32_f16(af, bf, acc[mt], 0, 0, 0);
        }
    }
    // lane (c,g) holds E[l][p]: l = mt*16 + 4g + r, p = pw + c.

    // ---------------- masked softmax over l ----------------
    float mx = -INFINITY;
    #pragma unroll
    for (int mt = 0; mt < 4; ++mt) {
        acc[mt][0] += mv[mt].x;  acc[mt][1] += mv[mt].y;
        acc[mt][2] += mv[mt].z;  acc[mt][3] += mv[mt].w;
        mx = fmaxf(mx, fmaxf(fmaxf(acc[mt][0], acc[mt][1]),
                             fmaxf(acc[mt][2], acc[mt][3])));
    }
    mx = fmaxf(mx, __shfl_xor(mx, 16, 64));
    mx = fmaxf(mx, __shfl_xor(mx, 32, 64));

    float sum = 0.f;
    #pragma unroll
    for (int mt = 0; mt < 4; ++mt) {
        #pragma unroll
        for (int r = 0; r < 4; ++r) {
            float e = exp2f((acc[mt][r] - mx) * 1.44269504f); // exp(-inf)=0 masked
            acc[mt][r] = e;
            sum += e;
        }
    }
    sum += __shfl_xor(sum, 16, 64);
    sum += __shfl_xor(sum, 32, 64);
    const float inv = 1.f / sum;
    #pragma unroll
    for (int mt = 0; mt < 4; ++mt) {
        acc[mt][0] *= inv; acc[mt][1] *= inv;
        acc[mt][2] *= inv; acc[mt][3] *= inv;
    }

    // attn_out[b][l][p] scalar stores (4 x 64B full sectors per instr)
    float* ab = attn_out + (size_t)b * LL * PP + pw + c;
    #pragma unroll
    for (int mt = 0; mt < 4; ++mt)
        #pragma unroll
        for (int r = 0; r < 4; ++r)
            ab[(size_t)(mt * 16 + 4 * g + r) * PP] = acc[mt][r];

    // prob -> fp16 per-wave LDS tile [p=c][l], pitch 72 (16B-aligned rows)
    f16* pl = s_prob + wv * (16 * 72) + c * 72;
    #pragma unroll
    for (int mt = 0; mt < 4; ++mt) {
        union { f16 h[2]; unsigned u; } z0, z1;
        z0.h[0] = (f16)acc[mt][0];  z0.h[1] = (f16)acc[mt][1];
        z1.h[0] = (f16)acc[mt][2];  z1.h[1] = (f16)acc[mt][3];
        uint2 uu; uu.x = z0.u; uu.y = z1.u;
        *reinterpret_cast<uint2*>(pl + mt * 16 + 4 * g) = uu;  // l = mt*16+4g..+3
    }
    // same-wave LDS exchange: DS ops complete in order per wave (verified
    // passing in round 4); no barrier needed.

    // ---------------- PV (swapped: A = prob, B = srcF) ----------------
    const f16* srcF_b = srcF + (size_t)b * IDF * LL;
    f32x4 acc2[8];
    #pragma unroll
    for (int mt = 0; mt < 8; ++mt) acc2[mt] = (f32x4){0.f, 0.f, 0.f, 0.f};

    #pragma unroll
    for (int ks = 0; ks < 2; ++ks) {
        // A-frag: prob[p = c][l = ks*32 + 8g + j]
        const f16x8 pa = *reinterpret_cast<const f16x8*>(pl + ks * 32 + 8 * g);
        #pragma unroll
        for (int mt = 0; mt < 8; ++mt) {
            // B-frag: B[k=l][n=i] = source[i = mt*16+c][l = ks*32+8g+j]
            const f16x8 sf = *reinterpret_cast<const f16x8*>(
                srcF_b + (size_t)(mt * 16 + c) * LL + ks * 32 + 8 * g);
            acc2[mt] = __builtin_amdgcn_mfma_f32_16x16x32_f16(pa, sf, acc2[mt], 0, 0, 0);
        }
    }
    // lane (c,g) holds weight[i = mt*16+c][p = pw + 4g + r] -> float4 stores

    float* wb = weight + (size_t)b * IDF * PP;
    #pragma unroll
    for (int mt = 0; mt < 8; ++mt) {
        float4 v; v.x = acc2[mt][0]; v.y = acc2[mt][1];
                  v.z = acc2[mt][2]; v.w = acc2[mt][3];
        *reinterpret_cast<float4*>(
            wb + (size_t)(mt * 16 + c) * PP + pw + 4 * g) = v;
    }
}

// ---------------------------------------------------------------------------
extern "C" void kernel_launch(void* const* d_in, const int* in_sizes, int n_in,
                              void* d_out, int out_size, void* d_ws, size_t ws_size,
                              hipStream_t stream) {
    const float*         x        = (const float*)d_in[0];
    const float*         ctx      = (const float*)d_in[1];
    const float*         Wm       = (const float*)d_in[2];
    const unsigned char* mask_raw = (const unsigned char*)d_in[3];

    float* weight   = (float*)d_out;                     // [B, IDF, H, W]
    float* attn_out = weight + (size_t)NB * IDF * PP;    // [B, L, H, W]

    // workspace: madd (4KB) | srcF fp16 (256KB) | srcT fp16 (256KB)
    float* madd = (float*)d_ws;
    f16*   srcF = (f16*)((char*)d_ws + 4096);
    f16*   srcT = srcF + (size_t)NB * IDF * LL;

    mask_prep_kernel<<<1, NB * LL, 0, stream>>>(mask_raw, madd);
    src_pack_kernel<<<(NB * IDF * LL) / 256, 256, 0, stream>>>(Wm, ctx, srcF, srcT);

    dim3 grid(PP / 64, NB);
    attn_mfma_kernel<<<grid, 256, 0, stream>>>(x, srcT, srcF, madd, weight, attn_out);
}

// Round 6
// 109.243 us; speedup vs baseline: 1.4041x; 1.4041x over previous
//
#include <hip/hip_runtime.h>
#include <hip/hip_bf16.h>
#include <hip/hip_fp16.h>

// Problem constants (AttentionModule: B=16, idf=128, cdf=256, H=W=128, L=64)
#define NB  16
#define IDF 128
#define CDF 256
#define LL  64
#define PP  16384      // H*W pixels per batch

typedef _Float16 f16;
typedef _Float16 f16x8 __attribute__((ext_vector_type(8)));
typedef float    f32x4 __attribute__((ext_vector_type(4)));

// ---------------------------------------------------------------------------
// Kernel 0: decode mask (int32 or uint8 on device) -> additive f32 table
// madd[16*64] (0 = keep, -inf = masked). Mask row for pixel p is p%16
// (torch tile(mask,(P,1)) quirk) — verified in rounds 2-5.
// ---------------------------------------------------------------------------
__global__ void mask_prep_kernel(const unsigned char* __restrict__ mask_raw,
                                 float* __restrict__ madd) {
    __shared__ int is_u8;
    const int k = threadIdx.x;            // 0..1023, one block
    if (k == 0) is_u8 = 0;
    __syncthreads();
    const unsigned char byte = mask_raw[k];
    if ((k & 3) != 0 && byte != 0) atomicOr(&is_u8, 1);
    __syncthreads();
    int masked;
    if (is_u8) masked = (byte != 0);
    else       masked = (((const int*)mask_raw)[k] != 0);
    madd[k] = masked ? -INFINITY : 0.0f;
}

// ---------------------------------------------------------------------------
// Kernel 1: source = W @ context (fp32 accum), emitted as fp16 in BOTH
// orientations: srcF[b][i][l] and srcT[b][l][i].
// ---------------------------------------------------------------------------
__global__ void src_pack_kernel(const float* __restrict__ Wm,
                                const float* __restrict__ ctx,
                                f16* __restrict__ srcF,
                                f16* __restrict__ srcT) {
    int g = blockIdx.x * 256 + threadIdx.x;      // 0 .. NB*IDF*LL-1
    int l = g & (LL - 1);
    int i = (g >> 6) & (IDF - 1);
    int b = g >> 13;
    const float* wrow = Wm + (size_t)i * CDF;
    const float* ccol = ctx + (size_t)b * CDF * LL + l;
    float s = 0.f;
    #pragma unroll 8
    for (int c = 0; c < CDF; ++c)
        s = fmaf(wrow[c], ccol[(size_t)c * LL], s);
    f16 h = (f16)s;
    srcF[g] = h;                                 // [b][i][l]
    srcT[((size_t)b * LL + l) * IDF + i] = h;    // [b][l][i]
}

// ---------------------------------------------------------------------------
// Kernel 2 (main): block = 4 waves = 64 pixels; wave = 16 pixels end-to-end.
// src staged ONCE per block in LDS (XOR-swizzled) -> fragment reads leave the
// vmem pipe. QK^T operands: A = x-frag, B = srcT-frag -> D[p][l], p=4g+r
// contiguous. Softmax reduces over the 16 c-lanes (shfl_xor 1/2/4/8).
// PV: A = prob (per-wave LDS tile), B = srcF -> D[p][i] -> float4 stores.
// ---------------------------------------------------------------------------
__global__ __launch_bounds__(256, 3)
void attn_mfma_kernel(const float* __restrict__ x,
                      const f16* __restrict__ srcT,
                      const f16* __restrict__ srcF,
                      const float* __restrict__ madd_g,
                      float* __restrict__ weight,
                      float* __restrict__ attn_out) {
    __shared__ __align__(16) unsigned char s_srcT[LL * 256];    // [l][i] f16, swz
    __shared__ __align__(16) unsigned char s_srcF[IDF * 128];   // [i][l] f16, swz
    __shared__ __align__(16) float s_mask[16 * 68];             // additive mask
    __shared__ __align__(16) f16   s_prob[4 * 16 * 72];         // per-wave [16 p][72]

    const int b    = blockIdx.y;
    const int tid  = threadIdx.x;
    const int wv   = tid >> 6;         // wave 0..3
    const int lane = tid & 63;
    const int c    = lane & 15;        // fragment n-index / row
    const int g    = lane >> 4;        // k-slice group 0..3
    const int cs   = (c & 7) << 4;     // read-side XOR swizzle (bytes)

    const int pw = blockIdx.x * 64 + wv * 16;            // wave's pixel base
    const float* xb = x + (size_t)b * IDF * PP + pw + c; // lane's x column

    // ---- issue all 32 x loads first (latency hides under staging+barrier)
    float xf[32];
    #pragma unroll
    for (int ks = 0; ks < 4; ++ks)
        #pragma unroll
        for (int j = 0; j < 8; ++j)
            xf[ks * 8 + j] = xb[(size_t)(ks * 32 + 8 * g + j) * PP];

    // ---- stage srcT (16KB) + srcF (16KB) + mask (4KB) into LDS, swizzled
    {
        const f16* sT = srcT + (size_t)b * LL * IDF;
        const f16* sF = srcF + (size_t)b * IDF * LL;
        #pragma unroll
        for (int it = 0; it < 4; ++it) {
            int e = (it * 256 + tid) * 8;          // f16 element offset
            int l = e >> 7, i = e & 127;           // srcT: [l][i]
            f16x8 v = *reinterpret_cast<const f16x8*>(sT + l * IDF + i);
            *reinterpret_cast<f16x8*>(
                s_srcT + l * 256 + ((i * 2) ^ ((l & 7) << 4))) = v;
        }
        #pragma unroll
        for (int it = 0; it < 4; ++it) {
            int e = (it * 256 + tid) * 8;
            int i = e >> 6, l = e & 63;            // srcF: [i][l]
            f16x8 v = *reinterpret_cast<const f16x8*>(sF + i * LL + l);
            *reinterpret_cast<f16x8*>(
                s_srcF + i * 128 + ((l * 2) ^ ((i & 7) << 4))) = v;
        }
        for (int k = tid; k < 16 * 64; k += 256)
            s_mask[(k >> 6) * 68 + (k & 63)] = madd_g[k];
    }
    __syncthreads();

    // ---------------- QK^T: D[p][l], A = x, B = srcT ----------------
    f32x4 acc[4];          // [nt] ; lane (c,g) reg r: p = pw+4g+r, l = nt*16+c
    #pragma unroll
    for (int nt = 0; nt < 4; ++nt) acc[nt] = (f32x4){0.f, 0.f, 0.f, 0.f};

    #pragma unroll
    for (int ks = 0; ks < 4; ++ks) {
        f16x8 xa;
        #pragma unroll
        for (int j = 0; j < 8; ++j) xa[j] = (f16)xf[ks * 8 + j];
        #pragma unroll
        for (int nt = 0; nt < 4; ++nt) {
            const f16x8 bt = *reinterpret_cast<const f16x8*>(
                s_srcT + (nt * 16 + c) * 256 + ((ks * 64 + 16 * g) ^ cs));
            acc[nt] = __builtin_amdgcn_mfma_f32_16x16x32_f16(xa, bt, acc[nt], 0, 0, 0);
        }
    }

    // ---------------- masked softmax over l (per p = 4g+r) ----------------
    #pragma unroll
    for (int nt = 0; nt < 4; ++nt)
        #pragma unroll
        for (int r = 0; r < 4; ++r)
            acc[nt][r] += s_mask[(4 * g + r) * 68 + nt * 16 + c];

    #pragma unroll
    for (int r = 0; r < 4; ++r) {
        float mx = fmaxf(fmaxf(acc[0][r], acc[1][r]),
                         fmaxf(acc[2][r], acc[3][r]));
        mx = fmaxf(mx, __shfl_xor(mx, 1, 64));
        mx = fmaxf(mx, __shfl_xor(mx, 2, 64));
        mx = fmaxf(mx, __shfl_xor(mx, 4, 64));
        mx = fmaxf(mx, __shfl_xor(mx, 8, 64));
        float sum = 0.f;
        #pragma unroll
        for (int nt = 0; nt < 4; ++nt) {
            float e = exp2f((acc[nt][r] - mx) * 1.44269504f); // exp(-inf)=0
            acc[nt][r] = e;
            sum += e;
        }
        sum += __shfl_xor(sum, 1, 64);
        sum += __shfl_xor(sum, 2, 64);
        sum += __shfl_xor(sum, 4, 64);
        sum += __shfl_xor(sum, 8, 64);
        const float inv = 1.f / sum;
        #pragma unroll
        for (int nt = 0; nt < 4; ++nt) acc[nt][r] *= inv;
    }

    // attn_out[b][l][p]: float4 per (nt): row l = nt*16+c, cols pw+4g..+3
    float* ab = attn_out + (size_t)b * LL * PP + pw;
    #pragma unroll
    for (int nt = 0; nt < 4; ++nt) {
        float4 v; v.x = acc[nt][0]; v.y = acc[nt][1];
                  v.z = acc[nt][2]; v.w = acc[nt][3];
        *reinterpret_cast<float4*>(ab + (size_t)(nt * 16 + c) * PP + 4 * g) = v;
    }

    // prob -> per-wave LDS tile [p-local][l], pitch 72 f16
    f16* pt = s_prob + wv * (16 * 72);
    #pragma unroll
    for (int nt = 0; nt < 4; ++nt)
        #pragma unroll
        for (int r = 0; r < 4; ++r)
            pt[(4 * g + r) * 72 + nt * 16 + c] = (f16)acc[nt][r];
    // same-wave LDS RAW: DS ops ordered per wave (proven rounds 4-5).

    // ---------------- PV: D[p][i], A = prob, B = srcF ----------------
    f32x4 acc2[8];         // [nt] ; lane (c,g) reg r: p = pw+4g+r, i = nt*16+c
    #pragma unroll
    for (int nt = 0; nt < 8; ++nt) acc2[nt] = (f32x4){0.f, 0.f, 0.f, 0.f};

    #pragma unroll
    for (int ks = 0; ks < 2; ++ks) {
        const f16x8 pa = *reinterpret_cast<const f16x8*>(
            pt + c * 72 + ks * 32 + 8 * g);
        #pragma unroll
        for (int nt = 0; nt < 8; ++nt) {
            const f16x8 sf = *reinterpret_cast<const f16x8*>(
                s_srcF + (nt * 16 + c) * 128 + ((ks * 64 + 16 * g) ^ cs));
            acc2[nt] = __builtin_amdgcn_mfma_f32_16x16x32_f16(pa, sf, acc2[nt], 0, 0, 0);
        }
    }

    // weight[b][i][p]: float4 per (nt): row i = nt*16+c, cols pw+4g..+3
    float* wb = weight + (size_t)b * IDF * PP + pw;
    #pragma unroll
    for (int nt = 0; nt < 8; ++nt) {
        float4 v; v.x = acc2[nt][0]; v.y = acc2[nt][1];
                  v.z = acc2[nt][2]; v.w = acc2[nt][3];
        *reinterpret_cast<float4*>(wb + (size_t)(nt * 16 + c) * PP + 4 * g) = v;
    }
}

// ---------------------------------------------------------------------------
extern "C" void kernel_launch(void* const* d_in, const int* in_sizes, int n_in,
                              void* d_out, int out_size, void* d_ws, size_t ws_size,
                              hipStream_t stream) {
    const float*         x        = (const float*)d_in[0];
    const float*         ctx      = (const float*)d_in[1];
    const float*         Wm       = (const float*)d_in[2];
    const unsigned char* mask_raw = (const unsigned char*)d_in[3];

    float* weight   = (float*)d_out;                     // [B, IDF, H, W]
    float* attn_out = weight + (size_t)NB * IDF * PP;    // [B, L, H, W]

    // workspace: madd (4KB) | srcF fp16 (256KB) | srcT fp16 (256KB)
    float* madd = (float*)d_ws;
    f16*   srcF = (f16*)((char*)d_ws + 4096);
    f16*   srcT = srcF + (size_t)NB * IDF * LL;

    mask_prep_kernel<<<1, NB * LL, 0, stream>>>(mask_raw, madd);
    src_pack_kernel<<<(NB * IDF * LL) / 256, 256, 0, stream>>>(Wm, ctx, srcF, srcT);

    dim3 grid(PP / 64, NB);
    attn_mfma_kernel<<<grid, 256, 0, stream>>>(x, srcT, srcF, madd, weight, attn_out);
}

// Round 7
// 93.141 us; speedup vs baseline: 1.6469x; 1.1729x over previous
//
#include <hip/hip_runtime.h>
#include <hip/hip_bf16.h>
#include <hip/hip_fp16.h>

// Problem constants (AttentionModule: B=16, idf=128, cdf=256, H=W=128, L=64)
#define NB  16
#define IDF 128
#define CDF 256
#define LL  64
#define PP  16384      // H*W pixels per batch
#define PXB 128        // pixels per block (consecutive)
#define XPITCH 132     // f32 pitch of the 32x128 transpose buffer

typedef _Float16 f16;
typedef _Float16 f16x4 __attribute__((ext_vector_type(4)));
typedef _Float16 f16x8 __attribute__((ext_vector_type(8)));
typedef float    f32x4 __attribute__((ext_vector_type(4)));

// ---------------------------------------------------------------------------
// Kernel 0: decode mask (int32 or uint8) -> 16 x u64 bitmask (bit l of row b).
// Mask row used by pixel p is p%16 (torch tile(mask,(P,1)) quirk, proven r2-6).
// ---------------------------------------------------------------------------
__global__ void mask_prep_kernel(const unsigned char* __restrict__ mask_raw,
                                 unsigned long long* __restrict__ mbits) {
    __shared__ int is_u8;
    const int k = threadIdx.x;            // 0..1023, one block
    if (k == 0) is_u8 = 0;
    if (k < 16) mbits[k] = 0ULL;
    __syncthreads();
    const unsigned char byte = mask_raw[k];
    if ((k & 3) != 0 && byte != 0) atomicOr(&is_u8, 1);
    __syncthreads();
    int masked;
    if (is_u8) masked = (byte != 0);
    else       masked = (((const int*)mask_raw)[k] != 0);
    if (masked) atomicOr(&mbits[k >> 6], 1ULL << (unsigned)(k & 63));
}

// ---------------------------------------------------------------------------
// Kernel 1: source = W @ context (fp32 accum) -> fp16 in both orientations.
// ---------------------------------------------------------------------------
__global__ void src_pack_kernel(const float* __restrict__ Wm,
                                const float* __restrict__ ctx,
                                f16* __restrict__ srcF,
                                f16* __restrict__ srcT) {
    int g = blockIdx.x * 256 + threadIdx.x;      // 0 .. NB*IDF*LL-1
    int l = g & (LL - 1);
    int i = (g >> 6) & (IDF - 1);
    int b = g >> 13;
    const float* wrow = Wm + (size_t)i * CDF;
    const float* ccol = ctx + (size_t)b * CDF * LL + l;
    float s = 0.f;
    #pragma unroll 8
    for (int c = 0; c < CDF; ++c)
        s = fmaf(wrow[c], ccol[(size_t)c * LL], s);
    f16 h = (f16)s;
    srcF[g] = h;                                 // [b][i][l]
    srcT[((size_t)b * LL + l) * IDF + i] = h;    // [b][l][i]
}

// ---------------------------------------------------------------------------
// Kernel 2 (main): block = 4 waves = 128 CONSECUTIVE pixels; wave = 32 px.
// MFMA layouts identical to round 6 (verified). All global stores go through
// a 32-row x 128-px LDS transpose chunk -> every store instr covers 512B
// contiguous runs (fix DRAM page thrash of 64B scattered writes).
// ---------------------------------------------------------------------------
__global__ __launch_bounds__(256, 3)
void attn_mfma_kernel(const float* __restrict__ x,
                      const f16* __restrict__ srcT,
                      const f16* __restrict__ srcF,
                      const unsigned long long* __restrict__ mbits,
                      float* __restrict__ weight,
                      float* __restrict__ attn_out) {
    __shared__ __align__(16) unsigned char s_srcT[LL * 256];    // [l][i] f16, swz
    __shared__ __align__(16) unsigned char s_srcF[IDF * 128];   // [i][l] f16, swz
    __shared__ __align__(16) unsigned char s_u[17408];          // prob tiles / xp

    float* s_xp = (float*)s_u;                       // [32][XPITCH] f32 chunk

    const int b    = blockIdx.y;
    const int tid  = threadIdx.x;
    const int wv   = tid >> 6;         // wave 0..3
    const int lane = tid & 63;
    const int c    = lane & 15;
    const int g    = lane >> 4;
    const int cs   = (c & 7) << 4;     // read-side XOR swizzle (bytes)

    f16* s_pw = (f16*)s_u + (size_t)wv * (32 * 68);  // per-wave prob [32px][68]

    const int pwb = blockIdx.x * PXB;                // block pixel base
    const int pww = pwb + wv * 32;                   // wave pixel base
    const float* xb0 = x + (size_t)b * IDF * PP + pww + c;        // pt=0
    const float* xb1 = xb0 + 16;                                  // pt=1

    // ---- mask bits for this lane's 4 pixel rows (p%16 = 4g+r)
    unsigned mlo[4], mhi[4];
    #pragma unroll
    for (int r = 0; r < 4; ++r) {
        unsigned long long m = mbits[4 * g + r];
        mlo[r] = (unsigned)m;
        mhi[r] = (unsigned)(m >> 32);
    }

    // ---- QK^T x-load pipeline macros (all-static indexing)
    float xfa[16], xfb[16];
#define QK_LOAD(BUF, KS)                                                  \
    {   _Pragma("unroll")                                                 \
        for (int j = 0; j < 8; ++j) {                                     \
            BUF[j]     = xb0[(size_t)((KS) * 32 + 8 * g + j) * PP];       \
            BUF[8 + j] = xb1[(size_t)((KS) * 32 + 8 * g + j) * PP];       \
        } }

    QK_LOAD(xfa, 0)          // issue first x loads before staging

    // ---- stage srcT (16KB) + srcF (16KB) into LDS, write-side swizzled
    {
        const f16* sT = srcT + (size_t)b * LL * IDF;
        const f16* sF = srcF + (size_t)b * IDF * LL;
        #pragma unroll
        for (int it = 0; it < 4; ++it) {
            int e = (it * 256 + tid) * 8;
            int l = e >> 7, i = e & 127;
            f16x8 v = *reinterpret_cast<const f16x8*>(sT + l * IDF + i);
            *reinterpret_cast<f16x8*>(
                s_srcT + l * 256 + ((i * 2) ^ ((l & 7) << 4))) = v;
        }
        #pragma unroll
        for (int it = 0; it < 4; ++it) {
            int e = (it * 256 + tid) * 8;
            int i = e >> 6, l = e & 63;
            f16x8 v = *reinterpret_cast<const f16x8*>(sF + i * LL + l);
            *reinterpret_cast<f16x8*>(
                s_srcF + i * 128 + ((l * 2) ^ ((i & 7) << 4))) = v;
        }
    }
    __syncthreads();   // B0

    // ---------------- QK^T: D[p][l], A = x (regs), B = srcT (LDS) --------
    f32x4 acc[2][4];   // [pt][nt]; lane(c,g) reg r: p = pww+pt*16+4g+r, l = nt*16+c
    #pragma unroll
    for (int pt = 0; pt < 2; ++pt)
        #pragma unroll
        for (int nt = 0; nt < 4; ++nt) acc[pt][nt] = (f32x4){0.f, 0.f, 0.f, 0.f};

#define QK_STEP(BUF, KS)                                                  \
    {   f16x8 xa0, xa1;                                                   \
        _Pragma("unroll")                                                 \
        for (int j = 0; j < 8; ++j) { xa0[j] = (f16)BUF[j];               \
                                      xa1[j] = (f16)BUF[8 + j]; }         \
        _Pragma("unroll")                                                 \
        for (int nt = 0; nt < 4; ++nt) {                                  \
            const f16x8 bt = *reinterpret_cast<const f16x8*>(             \
                s_srcT + (nt * 16 + c) * 256 + (((KS) * 64 + 16 * g) ^ cs)); \
            acc[0][nt] = __builtin_amdgcn_mfma_f32_16x16x32_f16(xa0, bt, acc[0][nt], 0, 0, 0); \
            acc[1][nt] = __builtin_amdgcn_mfma_f32_16x16x32_f16(xa1, bt, acc[1][nt], 0, 0, 0); \
        } }

    QK_LOAD(xfb, 1)
    QK_STEP(xfa, 0)
    QK_LOAD(xfa, 2)
    QK_STEP(xfb, 1)
    QK_LOAD(xfb, 3)
    QK_STEP(xfa, 2)
    QK_STEP(xfb, 3)

    // ---------------- masked softmax over l (per pixel = pt,4g+r) --------
    #pragma unroll
    for (int r = 0; r < 4; ++r) {
        const unsigned m0 = (mlo[r] >> c) & 1u;
        const unsigned m1 = (mlo[r] >> (16 + c)) & 1u;
        const unsigned m2 = (mhi[r] >> c) & 1u;
        const unsigned m3 = (mhi[r] >> (16 + c)) & 1u;
        #pragma unroll
        for (int pt = 0; pt < 2; ++pt) {
            if (m0) acc[pt][0][r] = -INFINITY;
            if (m1) acc[pt][1][r] = -INFINITY;
            if (m2) acc[pt][2][r] = -INFINITY;
            if (m3) acc[pt][3][r] = -INFINITY;
        }
    }
    #pragma unroll
    for (int pt = 0; pt < 2; ++pt) {
        #pragma unroll
        for (int r = 0; r < 4; ++r) {
            float mx = fmaxf(fmaxf(acc[pt][0][r], acc[pt][1][r]),
                             fmaxf(acc[pt][2][r], acc[pt][3][r]));
            mx = fmaxf(mx, __shfl_xor(mx, 1, 64));
            mx = fmaxf(mx, __shfl_xor(mx, 2, 64));
            mx = fmaxf(mx, __shfl_xor(mx, 4, 64));
            mx = fmaxf(mx, __shfl_xor(mx, 8, 64));
            float sum = 0.f;
            #pragma unroll
            for (int nt = 0; nt < 4; ++nt) {
                float e = exp2f((acc[pt][nt][r] - mx) * 1.44269504f);
                acc[pt][nt][r] = e;
                sum += e;
            }
            sum += __shfl_xor(sum, 1, 64);
            sum += __shfl_xor(sum, 2, 64);
            sum += __shfl_xor(sum, 4, 64);
            sum += __shfl_xor(sum, 8, 64);
            const float inv = 1.f / sum;
            #pragma unroll
            for (int nt = 0; nt < 4; ++nt) acc[pt][nt][r] *= inv;
        }
    }

    // ---- prob -> per-wave LDS tile [px-local][l] (pitch 68 f16), then read
    //      PV A-fragments back (same-wave RAW, proven r4-6). No barrier yet.
    #pragma unroll
    for (int pt = 0; pt < 2; ++pt)
        #pragma unroll
        for (int nt = 0; nt < 4; ++nt)
            #pragma unroll
            for (int r = 0; r < 4; ++r)
                s_pw[(pt * 16 + 4 * g + r) * 68 + nt * 16 + c] = (f16)acc[pt][nt][r];

    f16x8 pa[2][2];    // [pt][ks2]: A[m=p=c][k=l=ks2*32+8g+j]
    #pragma unroll
    for (int pt = 0; pt < 2; ++pt)
        #pragma unroll
        for (int ks = 0; ks < 2; ++ks) {
            const f16* pp = s_pw + (pt * 16 + c) * 68 + ks * 32 + 8 * g;
            f16x4 lo = *reinterpret_cast<const f16x4*>(pp);
            f16x4 hi = *reinterpret_cast<const f16x4*>(pp + 4);
            f16x8 v;
            #pragma unroll
            for (int j = 0; j < 4; ++j) { v[j] = lo[j]; v[4 + j] = hi[j]; }
            pa[pt][ks] = v;
        }

    __syncthreads();   // B1: all prob readbacks done; s_u becomes xp buffer

    // ---- chunk store helper: 32 rows x 128 px from s_xp -> global
#define STORE_CHUNK(GDST)                                                 \
    {   _Pragma("unroll")                                                 \
        for (int k = 0; k < 4; ++k) {                                     \
            int f = tid + k * 256;                                        \
            int row = f >> 5, col = f & 31;                               \
            float4 v = *reinterpret_cast<const float4*>(                  \
                s_xp + row * XPITCH + col * 4);                           \
            *reinterpret_cast<float4*>(                                   \
                (GDST) + (size_t)row * PP + col * 4) = v;                 \
        } }

    // ---------------- attn_out chunks (l rows 0..31, 32..63) -------------
    float* abase = attn_out + (size_t)b * LL * PP + pwb;
    #pragma unroll
    for (int a = 0; a < 2; ++a) {
        #pragma unroll
        for (int pt = 0; pt < 2; ++pt)
            #pragma unroll
            for (int ntl = 0; ntl < 2; ++ntl) {
                const int nt = a * 2 + ntl;
                float4 v;
                v.x = acc[pt][nt][0]; v.y = acc[pt][nt][1];
                v.z = acc[pt][nt][2]; v.w = acc[pt][nt][3];
                *reinterpret_cast<float4*>(
                    s_xp + (ntl * 16 + c) * XPITCH + wv * 32 + pt * 16 + 4 * g) = v;
            }
        __syncthreads();                       // xp writes done
        STORE_CHUNK(abase + (size_t)(a * 32) * PP)
        __syncthreads();                       // reads done, xp reusable
    }

    // ---------------- PV chunks: D[p][i], A = prob (regs), B = srcF ------
    float* wbase = weight + (size_t)b * IDF * PP + pwb;
    #pragma unroll
    for (int ch = 0; ch < 4; ++ch) {
        f32x4 a2[2][2];    // [pt][it]; p = pww+pt*16+4g+r, i = ch*32+it*16+c
        #pragma unroll
        for (int pt = 0; pt < 2; ++pt)
            #pragma unroll
            for (int it = 0; it < 2; ++it) a2[pt][it] = (f32x4){0.f, 0.f, 0.f, 0.f};
        #pragma unroll
        for (int ks = 0; ks < 2; ++ks)
            #pragma unroll
            for (int it = 0; it < 2; ++it) {
                const f16x8 sf = *reinterpret_cast<const f16x8*>(
                    s_srcF + (ch * 32 + it * 16 + c) * 128 + ((ks * 64 + 16 * g) ^ cs));
                a2[0][it] = __builtin_amdgcn_mfma_f32_16x16x32_f16(pa[0][ks], sf, a2[0][it], 0, 0, 0);
                a2[1][it] = __builtin_amdgcn_mfma_f32_16x16x32_f16(pa[1][ks], sf, a2[1][it], 0, 0, 0);
            }
        #pragma unroll
        for (int pt = 0; pt < 2; ++pt)
            #pragma unroll
            for (int it = 0; it < 2; ++it) {
                float4 v;
                v.x = a2[pt][it][0]; v.y = a2[pt][it][1];
                v.z = a2[pt][it][2]; v.w = a2[pt][it][3];
                *reinterpret_cast<float4*>(
                    s_xp + (it * 16 + c) * XPITCH + wv * 32 + pt * 16 + 4 * g) = v;
            }
        __syncthreads();                       // xp writes done
        STORE_CHUNK(wbase + (size_t)(ch * 32) * PP)
        if (ch < 3) __syncthreads();           // reads done, xp reusable
    }
}

// ---------------------------------------------------------------------------
extern "C" void kernel_launch(void* const* d_in, const int* in_sizes, int n_in,
                              void* d_out, int out_size, void* d_ws, size_t ws_size,
                              hipStream_t stream) {
    const float*         x        = (const float*)d_in[0];
    const float*         ctx      = (const float*)d_in[1];
    const float*         Wm       = (const float*)d_in[2];
    const unsigned char* mask_raw = (const unsigned char*)d_in[3];

    float* weight   = (float*)d_out;                     // [B, IDF, H, W]
    float* attn_out = weight + (size_t)NB * IDF * PP;    // [B, L, H, W]

    // workspace: mbits u64[16] | srcF fp16 (256KB) | srcT fp16 (256KB)
    unsigned long long* mbits = (unsigned long long*)d_ws;
    f16* srcF = (f16*)((char*)d_ws + 4096);
    f16* srcT = srcF + (size_t)NB * IDF * LL;

    mask_prep_kernel<<<1, NB * LL, 0, stream>>>(mask_raw, mbits);
    src_pack_kernel<<<(NB * IDF * LL) / 256, 256, 0, stream>>>(Wm, ctx, srcF, srcT);

    dim3 grid(PP / PXB, NB);
    attn_mfma_kernel<<<grid, 256, 0, stream>>>(x, srcT, srcF, mbits, weight, attn_out);
}

// Round 8
// 78.186 us; speedup vs baseline: 1.9619x; 1.1913x over previous
//
#include <hip/hip_runtime.h>
#include <hip/hip_bf16.h>
#include <hip/hip_fp16.h>

// Problem constants (AttentionModule: B=16, idf=128, cdf=256, H=W=128, L=64)
#define NB  16
#define IDF 128
#define CDF 256
#define LL  64
#define PP  16384      // H*W pixels per batch
#define PXB 256        // pixels per block (consecutive) -> 1KB store runs
#define XPITCH 260     // f32 pitch of the 16x256 transpose chunk

typedef _Float16 f16;
typedef _Float16 f16x4 __attribute__((ext_vector_type(4)));
typedef _Float16 f16x8 __attribute__((ext_vector_type(8)));
typedef float    f32x4 __attribute__((ext_vector_type(4)));

// ---------------------------------------------------------------------------
// Kernel 0: decode mask (int32 or uint8) -> 16 x u64 bitmask. Mask row used
// by pixel p is p%16 (torch tile(mask,(P,1)) quirk, proven r2-7).
// ---------------------------------------------------------------------------
__global__ void mask_prep_kernel(const unsigned char* __restrict__ mask_raw,
                                 unsigned long long* __restrict__ mbits) {
    __shared__ int is_u8;
    const int k = threadIdx.x;            // 0..1023, one block
    if (k == 0) is_u8 = 0;
    if (k < 16) mbits[k] = 0ULL;
    __syncthreads();
    const unsigned char byte = mask_raw[k];
    if ((k & 3) != 0 && byte != 0) atomicOr(&is_u8, 1);
    __syncthreads();
    int masked;
    if (is_u8) masked = (byte != 0);
    else       masked = (((const int*)mask_raw)[k] != 0);
    if (masked) atomicOr(&mbits[k >> 6], 1ULL << (unsigned)(k & 63));
}

// ---------------------------------------------------------------------------
// Kernel 1: source = W @ context (fp32 accum) -> fp16 in both orientations.
// ---------------------------------------------------------------------------
__global__ void src_pack_kernel(const float* __restrict__ Wm,
                                const float* __restrict__ ctx,
                                f16* __restrict__ srcF,
                                f16* __restrict__ srcT) {
    int g = blockIdx.x * 256 + threadIdx.x;      // 0 .. NB*IDF*LL-1
    int l = g & (LL - 1);
    int i = (g >> 6) & (IDF - 1);
    int b = g >> 13;
    const float* wrow = Wm + (size_t)i * CDF;
    const float* ccol = ctx + (size_t)b * CDF * LL + l;
    float s = 0.f;
    #pragma unroll 8
    for (int c = 0; c < CDF; ++c)
        s = fmaf(wrow[c], ccol[(size_t)c * LL], s);
    f16 h = (f16)s;
    srcF[g] = h;                                 // [b][i][l]
    srcT[((size_t)b * LL + l) * IDF + i] = h;    // [b][l][i]
}

// ---------------------------------------------------------------------------
// Kernel 2 (main): block = 4 waves = 256 CONSECUTIVE pixels; wave = 64 px
// (pt = 0..3 groups of 16). MFMA layouts identical to r6/r7 (verified).
// Outputs stream through double-buffered 16x256 LDS transpose chunks ->
// 1KB contiguous nontemporal store runs; chunk k+1 is built (incl. its PV
// MFMAs) while chunk k stores — one barrier per chunk.
// ---------------------------------------------------------------------------
__global__ __launch_bounds__(256, 2)
void attn_mfma_kernel(const float* __restrict__ x,
                      const f16* __restrict__ srcT,
                      const f16* __restrict__ srcF,
                      const unsigned long long* __restrict__ mbits,
                      float* __restrict__ weight,
                      float* __restrict__ attn_out) {
    __shared__ __align__(16) unsigned char s_srcT[LL * 256];    // [l][i] f16, swz
    __shared__ __align__(16) unsigned char s_srcF[IDF * 128];   // [i][l] f16, swz
    __shared__ __align__(16) unsigned char s_u[34816];          // prob / 2x xp

    float* s_xpA = (float*)s_u;                      // [16][XPITCH] f32
    float* s_xpB = (float*)(s_u + 16640);

    const int b    = blockIdx.y;
    const int tid  = threadIdx.x;
    const int wv   = tid >> 6;         // wave 0..3
    const int lane = tid & 63;
    const int c    = lane & 15;
    const int g    = lane >> 4;
    const int cs   = (c & 7) << 4;     // read-side XOR swizzle (bytes)

    f16* s_pw = (f16*)s_u + (size_t)wv * (64 * 68);  // per-wave prob [64px][68]

    const int pwb = blockIdx.x * PXB;                // block pixel base
    const int pww = pwb + wv * 64;                   // wave pixel base (64 px)
    const float* xb = x + (size_t)b * IDF * PP + pww + c;

    // ---- mask bits for this lane's pixel rows (p%16 = 4g+r)
    unsigned mlo[4], mhi[4];
    #pragma unroll
    for (int r = 0; r < 4; ++r) {
        unsigned long long m = mbits[4 * g + r];
        mlo[r] = (unsigned)m;
        mhi[r] = (unsigned)(m >> 32);
    }

    // ---- QK^T x-load / compute pipeline macros (all-static indexing)
    float xfa[32], xfb[32];
#define QK_LOAD(BUF, KS)                                                    \
    {   _Pragma("unroll")                                                   \
        for (int pt = 0; pt < 4; ++pt)                                      \
            _Pragma("unroll")                                               \
            for (int j = 0; j < 8; ++j)                                     \
                BUF[pt * 8 + j] =                                           \
                    xb[(size_t)((KS) * 32 + 8 * g + j) * PP + pt * 16];     \
    }

    QK_LOAD(xfa, 0)          // issue first x loads before staging

    // ---- stage srcT (16KB) + srcF (16KB) into LDS, write-side swizzled
    {
        const f16* sT = srcT + (size_t)b * LL * IDF;
        const f16* sF = srcF + (size_t)b * IDF * LL;
        #pragma unroll
        for (int it = 0; it < 4; ++it) {
            int e = (it * 256 + tid) * 8;
            int l = e >> 7, i = e & 127;
            f16x8 v = *reinterpret_cast<const f16x8*>(sT + l * IDF + i);
            *reinterpret_cast<f16x8*>(
                s_srcT + l * 256 + ((i * 2) ^ ((l & 7) << 4))) = v;
        }
        #pragma unroll
        for (int it = 0; it < 4; ++it) {
            int e = (it * 256 + tid) * 8;
            int i = e >> 6, l = e & 63;
            f16x8 v = *reinterpret_cast<const f16x8*>(sF + i * LL + l);
            *reinterpret_cast<f16x8*>(
                s_srcF + i * 128 + ((l * 2) ^ ((i & 7) << 4))) = v;
        }
    }
    __syncthreads();   // B0: staging done

    // ---------------- QK^T: D[p][l], A = x (regs), B = srcT (LDS) --------
    f32x4 acc[4][4];   // [pt][nt]; lane(c,g) reg r: p = pww+pt*16+4g+r, l = nt*16+c
    #pragma unroll
    for (int pt = 0; pt < 4; ++pt)
        #pragma unroll
        for (int nt = 0; nt < 4; ++nt) acc[pt][nt] = (f32x4){0.f, 0.f, 0.f, 0.f};

#define QK_STEP(BUF, KS)                                                    \
    {   f16x8 xa[4];                                                        \
        _Pragma("unroll")                                                   \
        for (int pt = 0; pt < 4; ++pt)                                      \
            _Pragma("unroll")                                               \
            for (int j = 0; j < 8; ++j) xa[pt][j] = (f16)BUF[pt * 8 + j];   \
        _Pragma("unroll")                                                   \
        for (int nt = 0; nt < 4; ++nt) {                                    \
            const f16x8 bt = *reinterpret_cast<const f16x8*>(               \
                s_srcT + (nt * 16 + c) * 256 + (((KS) * 64 + 16 * g) ^ cs));\
            _Pragma("unroll")                                               \
            for (int pt = 0; pt < 4; ++pt)                                  \
                acc[pt][nt] = __builtin_amdgcn_mfma_f32_16x16x32_f16(       \
                    xa[pt], bt, acc[pt][nt], 0, 0, 0);                      \
        } }

    QK_LOAD(xfb, 1)
    QK_STEP(xfa, 0)
    QK_LOAD(xfa, 2)
    QK_STEP(xfb, 1)
    QK_LOAD(xfb, 3)
    QK_STEP(xfa, 2)
    QK_STEP(xfb, 3)

    // ---------------- masked softmax over l (per pixel) ----------------
    #pragma unroll
    for (int r = 0; r < 4; ++r) {
        const unsigned m0 = (mlo[r] >> c) & 1u;
        const unsigned m1 = (mlo[r] >> (16 + c)) & 1u;
        const unsigned m2 = (mhi[r] >> c) & 1u;
        const unsigned m3 = (mhi[r] >> (16 + c)) & 1u;
        #pragma unroll
        for (int pt = 0; pt < 4; ++pt) {
            if (m0) acc[pt][0][r] = -INFINITY;
            if (m1) acc[pt][1][r] = -INFINITY;
            if (m2) acc[pt][2][r] = -INFINITY;
            if (m3) acc[pt][3][r] = -INFINITY;
        }
    }
    #pragma unroll
    for (int pt = 0; pt < 4; ++pt) {
        #pragma unroll
        for (int r = 0; r < 4; ++r) {
            float mx = fmaxf(fmaxf(acc[pt][0][r], acc[pt][1][r]),
                             fmaxf(acc[pt][2][r], acc[pt][3][r]));
            mx = fmaxf(mx, __shfl_xor(mx, 1, 64));
            mx = fmaxf(mx, __shfl_xor(mx, 2, 64));
            mx = fmaxf(mx, __shfl_xor(mx, 4, 64));
            mx = fmaxf(mx, __shfl_xor(mx, 8, 64));
            float sum = 0.f;
            #pragma unroll
            for (int nt = 0; nt < 4; ++nt) {
                float e = exp2f((acc[pt][nt][r] - mx) * 1.44269504f);
                acc[pt][nt][r] = e;
                sum += e;
            }
            sum += __shfl_xor(sum, 1, 64);
            sum += __shfl_xor(sum, 2, 64);
            sum += __shfl_xor(sum, 4, 64);
            sum += __shfl_xor(sum, 8, 64);
            const float inv = 1.f / sum;
            #pragma unroll
            for (int nt = 0; nt < 4; ++nt) acc[pt][nt][r] *= inv;
        }
    }

    // ---- prob -> per-wave LDS tile [p-local][l] (pitch 68 f16), read PV
    //      A-frags back (same-wave RAW, proven r4-7).
    #pragma unroll
    for (int pt = 0; pt < 4; ++pt)
        #pragma unroll
        for (int nt = 0; nt < 4; ++nt)
            #pragma unroll
            for (int r = 0; r < 4; ++r)
                s_pw[(pt * 16 + 4 * g + r) * 68 + nt * 16 + c] =
                    (f16)acc[pt][nt][r];

    f16x8 pa[4][2];    // [pt][ks]: A[m=p=c][k=l=ks*32+8g+j]
    #pragma unroll
    for (int pt = 0; pt < 4; ++pt)
        #pragma unroll
        for (int ks = 0; ks < 2; ++ks) {
            const f16* pp = s_pw + (pt * 16 + c) * 68 + ks * 32 + 8 * g;
            f16x4 lo = *reinterpret_cast<const f16x4*>(pp);
            f16x4 hi = *reinterpret_cast<const f16x4*>(pp + 4);
            f16x8 v;
            #pragma unroll
            for (int j = 0; j < 4; ++j) { v[j] = lo[j]; v[4 + j] = hi[j]; }
            pa[pt][ks] = v;
        }

    __syncthreads();   // B1: all prob readbacks done; s_u becomes xp buffers

    float* abase = attn_out + (size_t)b * LL * PP + pwb;
    float* wbase = weight + (size_t)b * IDF * PP + pwb;

    // ---- chunk fill: 16 rows x 256 px into xp (row = c, col = p-local)
#define FILL_ATTN(NT, XP)                                                   \
    {   _Pragma("unroll")                                                   \
        for (int pt = 0; pt < 4; ++pt)                                      \
            *reinterpret_cast<f32x4*>(                                      \
                (XP) + c * XPITCH + wv * 64 + pt * 16 + 4 * g) = acc[pt][NT]; }

#define FILL_PV(CH, XP)                                                     \
    {   f32x4 a2[4];                                                        \
        _Pragma("unroll")                                                   \
        for (int pt = 0; pt < 4; ++pt) a2[pt] = (f32x4){0.f, 0.f, 0.f, 0.f};\
        _Pragma("unroll")                                                   \
        for (int ks = 0; ks < 2; ++ks) {                                    \
            const f16x8 sf = *reinterpret_cast<const f16x8*>(               \
                s_srcF + ((CH) * 16 + c) * 128 + ((ks * 64 + 16 * g) ^ cs));\
            _Pragma("unroll")                                               \
            for (int pt = 0; pt < 4; ++pt)                                  \
                a2[pt] = __builtin_amdgcn_mfma_f32_16x16x32_f16(            \
                    pa[pt][ks], sf, a2[pt], 0, 0, 0);                       \
        }                                                                   \
        _Pragma("unroll")                                                   \
        for (int pt = 0; pt < 4; ++pt)                                      \
            *reinterpret_cast<f32x4*>(                                      \
                (XP) + c * XPITCH + wv * 64 + pt * 16 + 4 * g) = a2[pt]; }

#define FILL_CHUNK(K, XP)                                                   \
    {   if ((K) < 4) { FILL_ATTN((K), (XP)) }                               \
        else         { FILL_PV((K) - 4, (XP)) } }

#define STORE_CHUNK(K, XP)                                                  \
    {   float* dst = ((K) < 4)                                              \
            ? (abase + (size_t)((K) * 16) * PP)                             \
            : (wbase + (size_t)(((K) - 4) * 16) * PP);                      \
        _Pragma("unroll")                                                   \
        for (int k2 = 0; k2 < 4; ++k2) {                                    \
            int f = tid + k2 * 256;                                         \
            int row = f >> 6, u = f & 63;                                   \
            f32x4 v = *reinterpret_cast<const f32x4*>(                      \
                (XP) + row * XPITCH + u * 4);                               \
            __builtin_nontemporal_store(v,                                  \
                reinterpret_cast<f32x4*>(dst + (size_t)row * PP + u * 4));  \
        } }

    // ---- 12 chunks (4 attn + 8 PV), double-buffered, 1 barrier each
    FILL_CHUNK(0, s_xpA)
    __syncthreads();
    #pragma unroll
    for (int k = 0; k < 12; ++k) {
        float* xp_cur = (k & 1) ? s_xpB : s_xpA;
        float* xp_nxt = (k & 1) ? s_xpA : s_xpB;
        STORE_CHUNK(k, xp_cur)
        if (k < 11) { FILL_CHUNK(k + 1, xp_nxt) }
        if (k < 11) __syncthreads();
    }
}

// ---------------------------------------------------------------------------
extern "C" void kernel_launch(void* const* d_in, const int* in_sizes, int n_in,
                              void* d_out, int out_size, void* d_ws, size_t ws_size,
                              hipStream_t stream) {
    const float*         x        = (const float*)d_in[0];
    const float*         ctx      = (const float*)d_in[1];
    const float*         Wm       = (const float*)d_in[2];
    const unsigned char* mask_raw = (const unsigned char*)d_in[3];

    float* weight   = (float*)d_out;                     // [B, IDF, H, W]
    float* attn_out = weight + (size_t)NB * IDF * PP;    // [B, L, H, W]

    // workspace: mbits u64[16] | srcF fp16 (256KB) | srcT fp16 (256KB)
    unsigned long long* mbits = (unsigned long long*)d_ws;
    f16* srcF = (f16*)((char*)d_ws + 4096);
    f16* srcT = srcF + (size_t)NB * IDF * LL;

    mask_prep_kernel<<<1, NB * LL, 0, stream>>>(mask_raw, mbits);
    src_pack_kernel<<<(NB * IDF * LL) / 256, 256, 0, stream>>>(Wm, ctx, srcF, srcT);

    dim3 grid(PP / PXB, NB);
    attn_mfma_kernel<<<grid, 256, 0, stream>>>(x, srcT, srcF, mbits, weight, attn_out);
}

// Round 9
// 77.098 us; speedup vs baseline: 1.9896x; 1.0141x over previous
//
#include <hip/hip_runtime.h>
#include <hip/hip_bf16.h>
#include <hip/hip_fp16.h>

// Problem constants (AttentionModule: B=16, idf=128, cdf=256, H=W=128, L=64)
#define NB  16
#define IDF 128
#define CDF 256
#define LL  64
#define PP  16384      // H*W pixels per batch
#define PXB 256        // pixels per block (consecutive) -> 1KB store runs
#define XPITCH 260     // f32 pitch of the 16x256 transpose chunk

typedef _Float16 f16;
typedef _Float16 f16x4 __attribute__((ext_vector_type(4)));
typedef _Float16 f16x8 __attribute__((ext_vector_type(8)));
typedef float    f32x4 __attribute__((ext_vector_type(4)));

// ---------------------------------------------------------------------------
// Kernel 1 (merged prep): all blocks pack source = W @ context -> fp16 in
// both orientations; block 0 additionally decodes the mask (int32 or uint8)
// into a 16 x u64 bitmask. Mask row used by pixel p is p%16 (torch
// tile(mask,(P,1)) quirk, proven r2-8).
// ---------------------------------------------------------------------------
__global__ void src_pack_kernel(const float* __restrict__ Wm,
                                const float* __restrict__ ctx,
                                f16* __restrict__ srcF,
                                f16* __restrict__ srcT,
                                const unsigned char* __restrict__ mask_raw,
                                unsigned long long* __restrict__ mbits) {
    if (blockIdx.x == 0) {
        // ---- mask decode (threads cover k = tid, tid+256, ... tid+768)
        __shared__ int is_u8;
        const int tid = threadIdx.x;
        if (tid == 0) is_u8 = 0;
        if (tid < 16) mbits[tid] = 0ULL;
        __syncthreads();
        unsigned char byt[4];
        #pragma unroll
        for (int q = 0; q < 4; ++q) {
            int k = tid + q * 256;
            byt[q] = mask_raw[k];
            if ((k & 3) != 0 && byt[q] != 0) atomicOr(&is_u8, 1);
        }
        __syncthreads();
        #pragma unroll
        for (int q = 0; q < 4; ++q) {
            int k = tid + q * 256;
            int masked;
            if (is_u8) masked = (byt[q] != 0);
            else       masked = (((const int*)mask_raw)[k] != 0);
            if (masked) atomicOr(&mbits[k >> 6], 1ULL << (unsigned)(k & 63));
        }
    }

    int g = blockIdx.x * 256 + threadIdx.x;      // 0 .. NB*IDF*LL-1
    int l = g & (LL - 1);
    int i = (g >> 6) & (IDF - 1);
    int b = g >> 13;
    const float* wrow = Wm + (size_t)i * CDF;
    const float* ccol = ctx + (size_t)b * CDF * LL + l;
    float s = 0.f;
    #pragma unroll 8
    for (int c = 0; c < CDF; ++c)
        s = fmaf(wrow[c], ccol[(size_t)c * LL], s);
    f16 h = (f16)s;
    srcF[g] = h;                                 // [b][i][l]
    srcT[((size_t)b * LL + l) * IDF + i] = h;    // [b][l][i]
}

// ---------------------------------------------------------------------------
// Kernel 2 (main): block = 4 waves = 256 CONSECUTIVE pixels; wave = 64 px
// (pt = 0..3 groups of 16). MFMA layouts identical to r6-r8 (verified).
// Outputs stream through double-buffered 16x256 LDS transpose chunks ->
// 1KB contiguous nontemporal store runs; chunk k+1 is built (incl. its PV
// MFMAs) while chunk k stores — one barrier per chunk.
// NEW (r9): bijective XCD-chunk swizzle on blockIdx.x so each XCD owns 8
// consecutive pixel-blocks -> adjacent 1KB runs of each output row are
// emitted by one XCD close in time (DRAM page-merge at the MC).
// ---------------------------------------------------------------------------
__global__ __launch_bounds__(256, 2)
void attn_mfma_kernel(const float* __restrict__ x,
                      const f16* __restrict__ srcT,
                      const f16* __restrict__ srcF,
                      const unsigned long long* __restrict__ mbits,
                      float* __restrict__ weight,
                      float* __restrict__ attn_out) {
    __shared__ __align__(16) unsigned char s_srcT[LL * 256];    // [l][i] f16, swz
    __shared__ __align__(16) unsigned char s_srcF[IDF * 128];   // [i][l] f16, swz
    __shared__ __align__(16) unsigned char s_u[34816];          // prob / 2x xp

    float* s_xpA = (float*)s_u;                      // [16][XPITCH] f32
    float* s_xpB = (float*)(s_u + 16640);

    const int b    = blockIdx.y;
    const int tid  = threadIdx.x;
    const int wv   = tid >> 6;         // wave 0..3
    const int lane = tid & 63;
    const int c    = lane & 15;
    const int g    = lane >> 4;
    const int cs   = (c & 7) << 4;     // read-side XOR swizzle (bytes)

    f16* s_pw = (f16*)s_u + (size_t)wv * (64 * 68);  // per-wave prob [64px][68]

    // XCD-chunk swizzle: grid.x = 64 = 8 XCDs x 8 consecutive pixel-blocks
    const int bxs = (blockIdx.x & 7) * 8 + (blockIdx.x >> 3);
    const int pwb = bxs * PXB;                       // block pixel base
    const int pww = pwb + wv * 64;                   // wave pixel base (64 px)
    const float* xb = x + (size_t)b * IDF * PP + pww + c;

    // ---- mask bits for this lane's pixel rows (p%16 = 4g+r)
    unsigned mlo[4], mhi[4];
    #pragma unroll
    for (int r = 0; r < 4; ++r) {
        unsigned long long m = mbits[4 * g + r];
        mlo[r] = (unsigned)m;
        mhi[r] = (unsigned)(m >> 32);
    }

    // ---- QK^T x-load / compute pipeline macros (all-static indexing)
    float xfa[32], xfb[32];
#define QK_LOAD(BUF, KS)                                                    \
    {   _Pragma("unroll")                                                   \
        for (int pt = 0; pt < 4; ++pt)                                      \
            _Pragma("unroll")                                               \
            for (int j = 0; j < 8; ++j)                                     \
                BUF[pt * 8 + j] =                                           \
                    xb[(size_t)((KS) * 32 + 8 * g + j) * PP + pt * 16];     \
    }

    QK_LOAD(xfa, 0)          // issue first x loads before staging

    // ---- stage srcT (16KB) + srcF (16KB) into LDS, write-side swizzled
    {
        const f16* sT = srcT + (size_t)b * LL * IDF;
        const f16* sF = srcF + (size_t)b * IDF * LL;
        #pragma unroll
        for (int it = 0; it < 4; ++it) {
            int e = (it * 256 + tid) * 8;
            int l = e >> 7, i = e & 127;
            f16x8 v = *reinterpret_cast<const f16x8*>(sT + l * IDF + i);
            *reinterpret_cast<f16x8*>(
                s_srcT + l * 256 + ((i * 2) ^ ((l & 7) << 4))) = v;
        }
        #pragma unroll
        for (int it = 0; it < 4; ++it) {
            int e = (it * 256 + tid) * 8;
            int i = e >> 6, l = e & 63;
            f16x8 v = *reinterpret_cast<const f16x8*>(sF + i * LL + l);
            *reinterpret_cast<f16x8*>(
                s_srcF + i * 128 + ((l * 2) ^ ((i & 7) << 4))) = v;
        }
    }
    __syncthreads();   // B0: staging done

    // ---------------- QK^T: D[p][l], A = x (regs), B = srcT (LDS) --------
    f32x4 acc[4][4];   // [pt][nt]; lane(c,g) reg r: p = pww+pt*16+4g+r, l = nt*16+c
    #pragma unroll
    for (int pt = 0; pt < 4; ++pt)
        #pragma unroll
        for (int nt = 0; nt < 4; ++nt) acc[pt][nt] = (f32x4){0.f, 0.f, 0.f, 0.f};

#define QK_STEP(BUF, KS)                                                    \
    {   f16x8 xa[4];                                                        \
        _Pragma("unroll")                                                   \
        for (int pt = 0; pt < 4; ++pt)                                      \
            _Pragma("unroll")                                               \
            for (int j = 0; j < 8; ++j) xa[pt][j] = (f16)BUF[pt * 8 + j];   \
        _Pragma("unroll")                                                   \
        for (int nt = 0; nt < 4; ++nt) {                                    \
            const f16x8 bt = *reinterpret_cast<const f16x8*>(               \
                s_srcT + (nt * 16 + c) * 256 + (((KS) * 64 + 16 * g) ^ cs));\
            _Pragma("unroll")                                               \
            for (int pt = 0; pt < 4; ++pt)                                  \
                acc[pt][nt] = __builtin_amdgcn_mfma_f32_16x16x32_f16(       \
                    xa[pt], bt, acc[pt][nt], 0, 0, 0);                      \
        } }

    QK_LOAD(xfb, 1)
    QK_STEP(xfa, 0)
    QK_LOAD(xfa, 2)
    QK_STEP(xfb, 1)
    QK_LOAD(xfb, 3)
    QK_STEP(xfa, 2)
    QK_STEP(xfb, 3)

    // ---------------- masked softmax over l (per pixel) ----------------
    #pragma unroll
    for (int r = 0; r < 4; ++r) {
        const unsigned m0 = (mlo[r] >> c) & 1u;
        const unsigned m1 = (mlo[r] >> (16 + c)) & 1u;
        const unsigned m2 = (mhi[r] >> c) & 1u;
        const unsigned m3 = (mhi[r] >> (16 + c)) & 1u;
        #pragma unroll
        for (int pt = 0; pt < 4; ++pt) {
            if (m0) acc[pt][0][r] = -INFINITY;
            if (m1) acc[pt][1][r] = -INFINITY;
            if (m2) acc[pt][2][r] = -INFINITY;
            if (m3) acc[pt][3][r] = -INFINITY;
        }
    }
    #pragma unroll
    for (int pt = 0; pt < 4; ++pt) {
        #pragma unroll
        for (int r = 0; r < 4; ++r) {
            float mx = fmaxf(fmaxf(acc[pt][0][r], acc[pt][1][r]),
                             fmaxf(acc[pt][2][r], acc[pt][3][r]));
            mx = fmaxf(mx, __shfl_xor(mx, 1, 64));
            mx = fmaxf(mx, __shfl_xor(mx, 2, 64));
            mx = fmaxf(mx, __shfl_xor(mx, 4, 64));
            mx = fmaxf(mx, __shfl_xor(mx, 8, 64));
            float sum = 0.f;
            #pragma unroll
            for (int nt = 0; nt < 4; ++nt) {
                float e = exp2f((acc[pt][nt][r] - mx) * 1.44269504f);
                acc[pt][nt][r] = e;
                sum += e;
            }
            sum += __shfl_xor(sum, 1, 64);
            sum += __shfl_xor(sum, 2, 64);
            sum += __shfl_xor(sum, 4, 64);
            sum += __shfl_xor(sum, 8, 64);
            const float inv = 1.f / sum;
            #pragma unroll
            for (int nt = 0; nt < 4; ++nt) acc[pt][nt][r] *= inv;
        }
    }

    // ---- prob -> per-wave LDS tile [p-local][l] (pitch 68 f16), read PV
    //      A-frags back (same-wave RAW, proven r4-8).
    #pragma unroll
    for (int pt = 0; pt < 4; ++pt)
        #pragma unroll
        for (int nt = 0; nt < 4; ++nt)
            #pragma unroll
            for (int r = 0; r < 4; ++r)
                s_pw[(pt * 16 + 4 * g + r) * 68 + nt * 16 + c] =
                    (f16)acc[pt][nt][r];

    f16x8 pa[4][2];    // [pt][ks]: A[m=p=c][k=l=ks*32+8g+j]
    #pragma unroll
    for (int pt = 0; pt < 4; ++pt)
        #pragma unroll
        for (int ks = 0; ks < 2; ++ks) {
            const f16* pp = s_pw + (pt * 16 + c) * 68 + ks * 32 + 8 * g;
            f16x4 lo = *reinterpret_cast<const f16x4*>(pp);
            f16x4 hi = *reinterpret_cast<const f16x4*>(pp + 4);
            f16x8 v;
            #pragma unroll
            for (int j = 0; j < 4; ++j) { v[j] = lo[j]; v[4 + j] = hi[j]; }
            pa[pt][ks] = v;
        }

    __syncthreads();   // B1: all prob readbacks done; s_u becomes xp buffers

    float* abase = attn_out + (size_t)b * LL * PP + pwb;
    float* wbase = weight + (size_t)b * IDF * PP + pwb;

    // ---- chunk fill: 16 rows x 256 px into xp (row = c, col = p-local)
#define FILL_ATTN(NT, XP)                                                   \
    {   _Pragma("unroll")                                                   \
        for (int pt = 0; pt < 4; ++pt)                                      \
            *reinterpret_cast<f32x4*>(                                      \
                (XP) + c * XPITCH + wv * 64 + pt * 16 + 4 * g) = acc[pt][NT]; }

#define FILL_PV(CH, XP)                                                     \
    {   f32x4 a2[4];                                                        \
        _Pragma("unroll")                                                   \
        for (int pt = 0; pt < 4; ++pt) a2[pt] = (f32x4){0.f, 0.f, 0.f, 0.f};\
        _Pragma("unroll")                                                   \
        for (int ks = 0; ks < 2; ++ks) {                                    \
            const f16x8 sf = *reinterpret_cast<const f16x8*>(               \
                s_srcF + ((CH) * 16 + c) * 128 + ((ks * 64 + 16 * g) ^ cs));\
            _Pragma("unroll")                                               \
            for (int pt = 0; pt < 4; ++pt)                                  \
                a2[pt] = __builtin_amdgcn_mfma_f32_16x16x32_f16(            \
                    pa[pt][ks], sf, a2[pt], 0, 0, 0);                       \
        }                                                                   \
        _Pragma("unroll")                                                   \
        for (int pt = 0; pt < 4; ++pt)                                      \
            *reinterpret_cast<f32x4*>(                                      \
                (XP) + c * XPITCH + wv * 64 + pt * 16 + 4 * g) = a2[pt]; }

#define FILL_CHUNK(K, XP)                                                   \
    {   if ((K) < 4) { FILL_ATTN((K), (XP)) }                               \
        else         { FILL_PV((K) - 4, (XP)) } }

#define STORE_CHUNK(K, XP)                                                  \
    {   float* dst = ((K) < 4)                                              \
            ? (abase + (size_t)((K) * 16) * PP)                             \
            : (wbase + (size_t)(((K) - 4) * 16) * PP);                      \
        _Pragma("unroll")                                                   \
        for (int k2 = 0; k2 < 4; ++k2) {                                    \
            int f = tid + k2 * 256;                                         \
            int row = f >> 6, u = f & 63;                                   \
            f32x4 v = *reinterpret_cast<const f32x4*>(                      \
                (XP) + row * XPITCH + u * 4);                               \
            __builtin_nontemporal_store(v,                                  \
                reinterpret_cast<f32x4*>(dst + (size_t)row * PP + u * 4));  \
        } }

    // ---- 12 chunks (4 attn + 8 PV), double-buffered, 1 barrier each
    FILL_CHUNK(0, s_xpA)
    __syncthreads();
    #pragma unroll
    for (int k = 0; k < 12; ++k) {
        float* xp_cur = (k & 1) ? s_xpB : s_xpA;
        float* xp_nxt = (k & 1) ? s_xpA : s_xpB;
        STORE_CHUNK(k, xp_cur)
        if (k < 11) { FILL_CHUNK(k + 1, xp_nxt) }
        if (k < 11) __syncthreads();
    }
}

// ---------------------------------------------------------------------------
extern "C" void kernel_launch(void* const* d_in, const int* in_sizes, int n_in,
                              void* d_out, int out_size, void* d_ws, size_t ws_size,
                              hipStream_t stream) {
    const float*         x        = (const float*)d_in[0];
    const float*         ctx      = (const float*)d_in[1];
    const float*         Wm       = (const float*)d_in[2];
    const unsigned char* mask_raw = (const unsigned char*)d_in[3];

    float* weight   = (float*)d_out;                     // [B, IDF, H, W]
    float* attn_out = weight + (size_t)NB * IDF * PP;    // [B, L, H, W]

    // workspace: mbits u64[16] | srcF fp16 (256KB) | srcT fp16 (256KB)
    unsigned long long* mbits = (unsigned long long*)d_ws;
    f16* srcF = (f16*)((char*)d_ws + 4096);
    f16* srcT = srcF + (size_t)NB * IDF * LL;

    src_pack_kernel<<<(NB * IDF * LL) / 256, 256, 0, stream>>>(
        Wm, ctx, srcF, srcT, mask_raw, mbits);

    dim3 grid(PP / PXB, NB);
    attn_mfma_kernel<<<grid, 256, 0, stream>>>(x, srcT, srcF, mbits, weight, attn_out);
}